// Round 19
// baseline (278.248 us; speedup 1.0000x reference)
//
#include <hip/hip_runtime.h>
#include <hip/hip_bf16.h>

#define NS 16384   // batch
#define H 256      // hidden
#define TH 768     // 3H
#define PRED 24    // decode steps
#define LDA 272    // fallback kernel stride (R3-proven)
#define LDB 264    // decode_pipe stride: 132 dwords % 32 = 4 -> 2-way banks (free, m136)
#define WS_NEEDED (425984)

typedef short bf16x8 __attribute__((ext_vector_type(8)));
typedef float floatx4 __attribute__((ext_vector_type(4)));

__device__ __forceinline__ float b2f(unsigned short u) {
    return __uint_as_float(((unsigned int)u) << 16);
}
__device__ __forceinline__ unsigned short f2b(float f) {   // RTN-even bf16
    unsigned int u = __float_as_uint(f);
    return (unsigned short)((u + 0x7FFFu + ((u >> 16) & 1u)) >> 16);
}
__device__ __forceinline__ float fsig(float v) {
    return __builtin_amdgcn_rcpf(1.0f + __expf(-v));
}
__device__ __forceinline__ float ftanh(float v) {
    return 1.0f - 2.0f * __builtin_amdgcn_rcpf(1.0f + __expf(2.0f * v));
}
// DPP lane-shuffle helper — ctrl is a template param (must be ICE). R17-verified.
template <int CTRL>
__device__ __forceinline__ float dpp_f(float x) {
    return __uint_as_float((unsigned)__builtin_amdgcn_mov_dpp(
        (int)__float_as_uint(x), CTRL, 0xF, 0xF, true));
}
__device__ __forceinline__ float red16(float pv) {   // 16-lane sum, pure VALU
    pv += dpp_f<0xB1>(pv);    // lane^1
    pv += dpp_f<0x4E>(pv);    // lane^2
    pv += dpp_f<0x141>(pv);   // row_half_mirror
    pv += dpp_f<0x140>(pv);   // row_mirror
    return pv;
}

// ================= prep 1: rank-1 input-proj collapse + small vectors =================
__global__ void prep_proj(const void* __restrict__ WihP, const void* __restrict__ wprojP,
                          const void* __restrict__ bprojP, const void* __restrict__ bihP,
                          const void* __restrict__ bhhP, const void* __restrict__ woutP,
                          const void* __restrict__ boutP,
                          float* __restrict__ u, float* __restrict__ c,
                          float* __restrict__ bhn, float* __restrict__ wo,
                          float* __restrict__ b0) {
    const int j = blockIdx.x;        // 768
    const int lane = threadIdx.x;    // 64
    unsigned long long bm = __ballot(!(fabsf(b2f(((const unsigned short*)WihP)[lane])) <= 0.25f));
    const bool f32in = (bm != 0ull);

    float su = 0.f, sc = 0.f;
    if (f32in) {
        const float* row = (const float*)WihP + (size_t)j * H;
        const float* wp = (const float*)wprojP;
        const float* bp = (const float*)bprojP;
        for (int k = lane; k < H; k += 64) {
            float w = row[k];
            su = fmaf(w, wp[k], su); sc = fmaf(w, bp[k], sc);
        }
    } else {
        const unsigned short* row = (const unsigned short*)WihP + (size_t)j * H;
        const unsigned short* wp = (const unsigned short*)wprojP;
        const unsigned short* bp = (const unsigned short*)bprojP;
        for (int k = lane; k < H; k += 64) {
            float w = b2f(row[k]);
            su = fmaf(w, b2f(wp[k]), su); sc = fmaf(w, b2f(bp[k]), sc);
        }
    }
    for (int m = 32; m; m >>= 1) { su += __shfl_xor(su, m, 64); sc += __shfl_xor(sc, m, 64); }

    if (lane == 0) {
        float bih = f32in ? ((const float*)bihP)[j] : b2f(((const unsigned short*)bihP)[j]);
        float bhh = f32in ? ((const float*)bhhP)[j] : b2f(((const unsigned short*)bhhP)[j]);
        u[j] = su;
        c[j] = sc + bih + (j < 512 ? bhh : 0.f);
        if (j >= 512) bhn[j - 512] = bhh;
    }
    if (j < H && lane == 1)
        wo[j] = f32in ? ((const float*)woutP)[j] : b2f(((const unsigned short*)woutP)[j]);
    if (j == 0 && lane == 2)
        b0[0] = f32in ? ((const float*)boutP)[0] : b2f(((const unsigned short*)boutP)[0]);
}

// ======== prep 2: swizzle W_hh into MFMA-frag-contiguous bf16, 8-wave map (R9-R17) ======
// frag fi = ((w*8 + kk)*3 + g)*2 + s ; within frag: lane*8 shorts.
__global__ void prep_swz2(const void* __restrict__ WhhP, unsigned short* __restrict__ Wp) {
    const int cidx = blockIdx.x * 256 + threadIdx.x;   // 24576 chunks of 8 shorts
    unsigned long long bm = __ballot(!(fabsf(b2f(((const unsigned short*)WhhP)[threadIdx.x & 63])) <= 0.25f));
    const bool f32in = (bm != 0ull);

    const int lane = cidx & 63;
    const int fi   = cidx >> 6;         // 384 frags
    const int s    = fi & 1;
    const int g    = (fi >> 1) % 3;
    const int kk   = ((fi >> 1) / 3) & 7;
    const int w    = (fi >> 1) / 24;
    const size_t src = (size_t)(g * 256 + s * 128 + w * 16 + (lane & 15)) * H
                     + kk * 32 + (lane >> 4) * 8;
    unsigned short* dst = Wp + (size_t)cidx * 8;
    if (f32in) {
        const float* sp = (const float*)WhhP + src;
#pragma unroll
        for (int e = 0; e < 8; ++e) dst[e] = f2b(sp[e]);
    } else {
        const unsigned short* sp = (const unsigned short*)WhhP + src;
#pragma unroll
        for (int e = 0; e < 8; ++e) dst[e] = sp[e];
    }
}

// ====== fused 24-step decode: R15 pipeline + DPP pred-reduction + LDB=264 (R17-best) ======
// 512 blocks x 512 thr (8 waves), 32 rows, 1 block/CU, 2 rounds.  Tile A = rows 0-15,
// tile B = rows 16-31, phase-shifted half a step. W on-CU: kk0-5 in 144 regs,
// kk6-7 wave-private LDS. Pred reduction via DPP butterfly (VALU-only).
__global__ __launch_bounds__(512, 2)
void decode_pipe(const void* __restrict__ encP, const void* __restrict__ WihP,
                 const unsigned short* __restrict__ Wp,
                 const float* __restrict__ u, const float* __restrict__ c,
                 const float* __restrict__ bhnA, const float* __restrict__ woA,
                 const float* __restrict__ b0A, void* __restrict__ outP) {
    __shared__ __align__(16) unsigned short As[32 * LDB];     // 16.9 KB h tile (in-place)
    __shared__ __align__(16) unsigned short Wl[8][6144];      // 96 KB kk6-7 W, wave-private
    __shared__ float pred_part[8][32];
    __shared__ float pred_fin[32];
    __shared__ float pred_out[32][PRED];                      // 3 KB
    __shared__ int sflag;

    const int tid  = threadIdx.x;
    const int w    = tid >> 6;     // 0..7
    const int lane = tid & 63;
    const int lo   = lane & 15;
    const int quad = lane >> 4;
    const int m0   = blockIdx.x * 32;

    if (tid == 0) sflag = 0;
    __syncthreads();
    if (!(fabsf(b2f(((const unsigned short*)WihP)[tid])) <= 0.25f)) sflag = 1;
    __syncthreads();
    const bool f32in = (sflag != 0);

    const float*          encF = (const float*)encP;
    const unsigned short* encB = (const unsigned short*)encP;

    // stage h0 tile (bf16)
    for (int i = tid; i < 32 * H; i += 512) {
        int r = i >> 8, col = i & 255;
        float hv = f32in ? encF[(size_t)(m0 + r) * H + col] : b2f(encB[(size_t)(m0 + r) * H + col]);
        As[r * LDB + col] = f2b(hv);
    }
    if (tid < 32) pred_fin[tid] = 0.f;   // start token x=0

    // per-lane gate constants, jj(s) = s*128 + 16w + lo (R9-R17-verified)
    float ur[2], uz[2], un[2], cr[2], cz[2], cn[2], bh[2], wov[2];
#pragma unroll
    for (int s = 0; s < 2; ++s) {
        const int jj = s * 128 + w * 16 + lo;
        ur[s] = u[jj];       uz[s] = u[256 + jj];       un[s] = u[512 + jj];
        cr[s] = c[jj];       cz[s] = c[256 + jj];       cn[s] = c[512 + jj];
        bh[s] = bhnA[jj];    wov[s] = woA[jj];
    }
    const float b0 = b0A[0];

    // ---- one-time W residency load (R11-verified): kk0-5 regs, kk6-7 wave-private LDS ----
    const unsigned short* wp = Wp + (size_t)w * 24576 + lane * 8;  // + frag*512
    bf16x8 bW[6][3][2];                                            // 144 regs
#pragma unroll
    for (int kk = 0; kk < 6; ++kk)
#pragma unroll
        for (int g = 0; g < 3; ++g)
#pragma unroll
            for (int s = 0; s < 2; ++s)
                bW[kk][g][s] = *(const bf16x8*)(wp + (size_t)((kk * 3 + g) * 2 + s) * 512);
#pragma unroll
    for (int kk = 6; kk < 8; ++kk)
#pragma unroll
        for (int g = 0; g < 3; ++g)
#pragma unroll
            for (int s = 0; s < 2; ++s) {
                bf16x8 v = *(const bf16x8*)(wp + (size_t)((kk * 3 + g) * 2 + s) * 512);
                *(bf16x8*)&Wl[w][(((kk - 6) * 3 + g) * 2 + s) * 512 + lane * 8] = v;
            }
    __syncthreads();   // h0 + Wl visible

#define KLOOP(ACC, IM)                                                                    \
    do {                                                                                  \
        _Pragma("unroll")                                                                 \
        for (int g = 0; g < 3; ++g)                                                       \
            _Pragma("unroll")                                                             \
            for (int s = 0; s < 2; ++s) ACC[g][s] = (floatx4){0.f, 0.f, 0.f, 0.f};        \
        _Pragma("unroll")                                                                 \
        for (int kk = 0; kk < 8; ++kk) {                                                  \
            bf16x8 a = *(const bf16x8*)&As[((IM) * 16 + lo) * LDB + kk * 32 + quad * 8];  \
            if (kk < 6) {                                                                 \
                _Pragma("unroll")                                                         \
                for (int g = 0; g < 3; ++g)                                               \
                    _Pragma("unroll")                                                     \
                    for (int s = 0; s < 2; ++s)                                           \
                        ACC[g][s] = __builtin_amdgcn_mfma_f32_16x16x32_bf16(              \
                            a, bW[kk][g][s], ACC[g][s], 0, 0, 0);                         \
            } else {                                                                      \
                _Pragma("unroll")                                                         \
                for (int g = 0; g < 3; ++g)                                               \
                    _Pragma("unroll")                                                     \
                    for (int s = 0; s < 2; ++s) {                                         \
                        bf16x8 b = *(const bf16x8*)&Wl[w][(((kk - 6) * 3 + g) * 2 + s) * 512 + lane * 8]; \
                        ACC[g][s] = __builtin_amdgcn_mfma_f32_16x16x32_bf16(              \
                            a, b, ACC[g][s], 0, 0, 0);                                    \
                    }                                                                     \
            }                                                                             \
        }                                                                                 \
    } while (0)

#define EPILOG(ACC, IM)                                                                   \
    do {                                                                                  \
        _Pragma("unroll")                                                                 \
        for (int v = 0; v < 4; ++v) {                                                     \
            const int row = (IM) * 16 + quad * 4 + v;                                     \
            const float xv = pred_fin[row];                                               \
            float pv = 0.f;                                                               \
            _Pragma("unroll")                                                             \
            for (int s = 0; s < 2; ++s) {                                                 \
                const int jj = s * 128 + w * 16 + lo;                                     \
                const int hofs = row * LDB + jj;                                          \
                const float hold = b2f(As[hofs]);                                         \
                float r  = fsig(fmaf(xv, ur[s], cr[s]) + ACC[0][s][v]);                   \
                float z  = fsig(fmaf(xv, uz[s], cz[s]) + ACC[1][s][v]);                   \
                float n  = ftanh(fmaf(xv, un[s], cn[s]) + r * (ACC[2][s][v] + bh[s]));    \
                float hn = fmaf(z, hold - n, n);                                          \
                As[hofs] = f2b(hn);                                                       \
                pv = fmaf(hn, wov[s], pv);                                                \
            }                                                                             \
            pv = red16(pv);                  /* DPP butterfly: VALU-only 16-lane sum */   \
            if (lo == 0) pred_part[w][row] = pv;                                          \
        }                                                                                 \
    } while (0)

    floatx4 accA[3][2], accB[3][2];
    KLOOP(accA, 0);   // preamble: K(A,0) — h(A,0) staged, barrier above

#pragma unroll 1
    for (int t = 0; t < PRED; ++t) {
        // ---- phase 1: finalize(B,t-1) + epi(A,t) + K(B,t) ----
        if (t > 0 && tid >= 16 && tid < 32) {
            float pr = b0;
#pragma unroll
            for (int ww = 0; ww < 8; ++ww) pr += pred_part[ww][tid];
            pred_fin[tid] = pr;
            pred_out[tid][t - 1] = pr;
        }
        EPILOG(accA, 0);
        KLOOP(accB, 1);
        __syncthreads();

        // ---- phase 2: finalize(A,t) + epi(B,t) + K(A,t+1) ----
        if (tid < 16) {
            float pr = b0;
#pragma unroll
            for (int ww = 0; ww < 8; ++ww) pr += pred_part[ww][tid];
            pred_fin[tid] = pr;
            pred_out[tid][t] = pr;
        }
        EPILOG(accB, 1);
        if (t < PRED - 1) KLOOP(accA, 0);
        __syncthreads();
    }

    // ---- postamble: finalize(B, t=23) ----
    if (tid >= 16 && tid < 32) {
        float pr = b0;
#pragma unroll
        for (int ww = 0; ww < 8; ++ww) pr += pred_part[ww][tid];
        pred_out[tid][PRED - 1] = pr;
    }
    __syncthreads();

    // single coalesced output store
    for (int i = tid; i < 32 * PRED; i += 512) {
        int row = i / PRED, tt = i % PRED;
        float pr = pred_out[row][tt];
        if (f32in) ((float*)outP)[(size_t)(m0 + row) * PRED + tt] = pr;
        else ((unsigned short*)outP)[(size_t)(m0 + row) * PRED + tt] = f2b(pr);
    }
#undef KLOOP
#undef EPILOG
}

// ================= fallback (R3, proven): zero-workspace fused decode =================
__global__ __launch_bounds__(512, 2)
void decode_all(const void* __restrict__ encP,   const void* __restrict__ wprojP,
                const void* __restrict__ bprojP, const void* __restrict__ WihP,
                const void* __restrict__ bihP,   const void* __restrict__ WhhP,
                const void* __restrict__ bhhP,   const void* __restrict__ woutP,
                const void* __restrict__ boutP,  void* __restrict__ outP) {
    __shared__ __align__(16) unsigned short Asf[64 * LDA];
    __shared__ float u_lds[TH], c_lds[TH];
    __shared__ float bhn_lds[H], wo_lds[H];
    __shared__ float wp_lds[H], bp_lds[H];
    __shared__ float pred_lds[2][64];
    __shared__ int sflag;

    const int tid  = threadIdx.x;
    const int wid  = tid >> 6;
    const int lane = tid & 63;
    const int lo   = lane & 15;
    const int quad = lane >> 4;
    const int rh   = wid & 3;
    const int ch   = wid >> 2;
    const int m0   = blockIdx.x * 64;

    if (tid == 0) sflag = 0;
    __syncthreads();
    if (!(fabsf(b2f(((const unsigned short*)WihP)[tid])) <= 0.25f)) sflag = 1;
    __syncthreads();
    const bool f32in = (sflag != 0);

    const float*          encF = (const float*)encP;
    const unsigned short* encB = (const unsigned short*)encP;
    const unsigned short* WhhB = (const unsigned short*)WhhP;
    const float*          WhhF = (const float*)WhhP;

    if (tid < H) {
        wp_lds[tid] = f32in ? ((const float*)wprojP)[tid] : b2f(((const unsigned short*)wprojP)[tid]);
        bp_lds[tid] = f32in ? ((const float*)bprojP)[tid] : b2f(((const unsigned short*)bprojP)[tid]);
        wo_lds[tid] = f32in ? ((const float*)woutP)[tid]  : b2f(((const unsigned short*)woutP)[tid]);
    }
    __syncthreads();

    for (int j = tid; j < TH; j += 512) {
        float su = 0.f, sc = 0.f;
        if (f32in) {
            const float* row = (const float*)WihP + (size_t)j * H;
            for (int k = 0; k < H; ++k) { float w = row[k]; su = fmaf(w, wp_lds[k], su); sc = fmaf(w, bp_lds[k], sc); }
        } else {
            const unsigned short* row = (const unsigned short*)WihP + (size_t)j * H;
            for (int k = 0; k < H; ++k) { float w = b2f(row[k]); su = fmaf(w, wp_lds[k], su); sc = fmaf(w, bp_lds[k], sc); }
        }
        float bih = f32in ? ((const float*)bihP)[j] : b2f(((const unsigned short*)bihP)[j]);
        float bhh = f32in ? ((const float*)bhhP)[j] : b2f(((const unsigned short*)bhhP)[j]);
        u_lds[j] = su;
        c_lds[j] = sc + bih + (j < 512 ? bhh : 0.f);
        if (j >= 512) bhn_lds[j - 512] = bhh;
    }

    for (int i = tid; i < 64 * H; i += 512) {
        int r = i >> 8, col = i & 255;
        float hv = f32in ? encF[(size_t)(m0 + r) * H + col] : b2f(encB[(size_t)(m0 + r) * H + col]);
        Asf[r * LDA + col] = f2b(hv);
    }
    float hold[8][4];
#pragma unroll
    for (int s = 0; s < 8; ++s)
#pragma unroll
        for (int v = 0; v < 4; ++v) {
            int row = m0 + rh * 16 + quad * 4 + v;
            int jj  = ch * 128 + s * 16 + lo;
            hold[s][v] = f32in ? encF[(size_t)row * H + jj] : b2f(encB[(size_t)row * H + jj]);
        }
    const float b0 = f32in ? ((const float*)boutP)[0] : b2f(((const unsigned short*)boutP)[0]);

    float xm[4] = {0.f, 0.f, 0.f, 0.f};
    __syncthreads();

    const int aBase = (rh * 16 + lo) * LDA;
    const int wCol0 = ch * 128 + lo;

#pragma unroll 1
    for (int t = 0; t < PRED; ++t) {
        floatx4 acc[3][8];
#pragma unroll
        for (int g = 0; g < 3; ++g)
#pragma unroll
            for (int s = 0; s < 8; ++s) acc[g][s] = (floatx4){0.f, 0.f, 0.f, 0.f};

        if (f32in) {
#pragma unroll 1
            for (int kk = 0; kk < 8; ++kk) {
                bf16x8 a = *(const bf16x8*)&Asf[aBase + kk * 32 + quad * 8];
#pragma unroll
                for (int g = 0; g < 3; ++g)
#pragma unroll
                    for (int s = 0; s < 8; ++s) {
                        const float* wr = WhhF + (size_t)(g * 256 + wCol0 + s * 16) * H + kk * 32 + quad * 8;
                        float4 w0 = *(const float4*)wr;
                        float4 w1 = *(const float4*)(wr + 4);
                        bf16x8 b;
                        b[0] = (short)f2b(w0.x); b[1] = (short)f2b(w0.y);
                        b[2] = (short)f2b(w0.z); b[3] = (short)f2b(w0.w);
                        b[4] = (short)f2b(w1.x); b[5] = (short)f2b(w1.y);
                        b[6] = (short)f2b(w1.z); b[7] = (short)f2b(w1.w);
                        acc[g][s] = __builtin_amdgcn_mfma_f32_16x16x32_bf16(a, b, acc[g][s], 0, 0, 0);
                    }
            }
        } else {
#pragma unroll 1
            for (int kk = 0; kk < 8; ++kk) {
                bf16x8 a = *(const bf16x8*)&Asf[aBase + kk * 32 + quad * 8];
#pragma unroll
                for (int g = 0; g < 3; ++g)
#pragma unroll
                    for (int s = 0; s < 8; ++s) {
                        bf16x8 b = *(const bf16x8*)(WhhB + (size_t)(g * 256 + wCol0 + s * 16) * H + kk * 32 + quad * 8);
                        acc[g][s] = __builtin_amdgcn_mfma_f32_16x16x32_bf16(a, b, acc[g][s], 0, 0, 0);
                    }
            }
        }
        __syncthreads();

        float pp[4] = {0.f, 0.f, 0.f, 0.f};
#pragma unroll
        for (int s = 0; s < 8; ++s) {
            const int jj = ch * 128 + s * 16 + lo;
            const float urr = u_lds[jj], uzz = u_lds[256 + jj], unn = u_lds[512 + jj];
            const float crr = c_lds[jj], czz = c_lds[256 + jj], cnn = c_lds[512 + jj];
            const float bhn = bhn_lds[jj], wovv = wo_lds[jj];
#pragma unroll
            for (int v = 0; v < 4; ++v) {
                const float xv = xm[v];
                float r  = fsig(fmaf(xv, urr, crr) + acc[0][s][v]);
                float z  = fsig(fmaf(xv, uzz, czz) + acc[1][s][v]);
                float n  = ftanh(fmaf(xv, unn, cnn) + r * (acc[2][s][v] + bhn));
                float hn = fmaf(z, hold[s][v] - n, n);
                hold[s][v] = hn;
                Asf[(rh * 16 + quad * 4 + v) * LDA + jj] = f2b(hn);
                pp[v] = fmaf(hn, wovv, pp[v]);
            }
        }
#pragma unroll
        for (int v = 0; v < 4; ++v) {
            float pv = pp[v];
            pv += __shfl_xor(pv, 1, 64);
            pv += __shfl_xor(pv, 2, 64);
            pv += __shfl_xor(pv, 4, 64);
            pv += __shfl_xor(pv, 8, 64);
            if (lo == 0) pred_lds[ch][rh * 16 + quad * 4 + v] = pv;
        }
        __syncthreads();

#pragma unroll
        for (int v = 0; v < 4; ++v) {
            const int ml = rh * 16 + quad * 4 + v;
            xm[v] = b0 + pred_lds[0][ml] + pred_lds[1][ml];
        }
        if (tid < 64) {
            float pr = b0 + pred_lds[0][tid] + pred_lds[1][tid];
            if (f32in) ((float*)outP)[(size_t)(m0 + tid) * PRED + t] = pr;
            else ((unsigned short*)outP)[(size_t)(m0 + tid) * PRED + t] = f2b(pr);
        }
    }
}

extern "C" void kernel_launch(void* const* d_in, const int* in_sizes, int n_in,
                              void* d_out, int out_size, void* d_ws, size_t ws_size,
                              hipStream_t stream) {
    if (ws_size >= (size_t)WS_NEEDED) {
        char* ws = (char*)d_ws;
        unsigned short* Wp = (unsigned short*)ws;          // 393216 B
        float* u   = (float*)(ws + 393216);                // 3072 B
        float* c   = (float*)(ws + 396288);                // 3072 B
        float* bhn = (float*)(ws + 399360);                // 1024 B
        float* wo  = (float*)(ws + 400384);                // 1024 B
        float* b0  = (float*)(ws + 401408);                // 4 B
        prep_proj<<<TH, 64, 0, stream>>>(d_in[3], d_in[1], d_in[2], d_in[4], d_in[6],
                                         d_in[7], d_in[8], u, c, bhn, wo, b0);
        prep_swz2<<<96, 256, 0, stream>>>(d_in[5], Wp);
        decode_pipe<<<NS / 32, 512, 0, stream>>>(d_in[0], d_in[3], Wp, u, c, bhn, wo, b0, d_out);
    } else {
        decode_all<<<NS / 64, 512, 0, stream>>>(d_in[0], d_in[1], d_in[2], d_in[3],
                                                d_in[4], d_in[5], d_in[6], d_in[7],
                                                d_in[8], d_out);
    }
}